// Round 1
// baseline (229.328 us; speedup 1.0000x reference)
//
#include <hip/hip_runtime.h>
#include <math.h>

#define NB 1024  // batch

// ---------------------------------------------------------------------------
// K0: transpose x (B, C*H*W=3072) -> xT (3072, B), 64x64 LDS tiles
// ---------------------------------------------------------------------------
__global__ __launch_bounds__(256) void k_transpose(const float* __restrict__ x,
                                                   float* __restrict__ xT) {
  __shared__ float tile[64][65];
  const int c0 = blockIdx.x * 64;   // chw tile
  const int b0 = blockIdx.y * 64;   // batch tile
  const int tx = threadIdx.x & 63;
  const int ty = threadIdx.x >> 6;
#pragma unroll
  for (int r = 0; r < 16; ++r) {
    const int bb = r * 4 + ty;
    tile[bb][tx] = x[(size_t)(b0 + bb) * 3072 + c0 + tx];  // coalesced over chw
  }
  __syncthreads();
#pragma unroll
  for (int r = 0; r < 16; ++r) {
    const int cc = r * 4 + ty;
    xT[(size_t)(c0 + cc) * NB + b0 + tx] = tile[tx][cc];   // coalesced over b
  }
}

// ---------------------------------------------------------------------------
// K1: untied conv1 (C=3,k=5, 32x32 -> 28x28, O=6) + bias + relu + 2x2 maxpool
//     xT: (3,32,32,B)  w1: (6,3,28,28,25)  b1: (6,28,28)  h1: (6,14,14,B)
//     block = 256 lanes of b; blockIdx.x = pooled position (14x14); .y = bgroup
// ---------------------------------------------------------------------------
__global__ __launch_bounds__(256) void k_conv1(const float* __restrict__ xT,
                                               const float* __restrict__ w1,
                                               const float* __restrict__ b1,
                                               float* __restrict__ h1) {
  const int pos = blockIdx.x;            // 0..195
  const int ph = pos / 14, pw = pos % 14;
  const int b = blockIdx.y * 256 + threadIdx.x;

  float acc[6][2][2];
#pragma unroll
  for (int o = 0; o < 6; ++o)
#pragma unroll
    for (int i = 0; i < 2; ++i)
#pragma unroll
      for (int j = 0; j < 2; ++j) acc[o][i][j] = 0.f;

  for (int c = 0; c < 3; ++c) {
    // 6x6 input window for this channel, registers, coalesced loads over b
    float xw[6][6];
#pragma unroll
    for (int dh = 0; dh < 6; ++dh)
#pragma unroll
      for (int dw = 0; dw < 6; ++dw)
        xw[dh][dw] =
            xT[((size_t)(c * 32 + (2 * ph + dh)) * 32 + (2 * pw + dw)) * NB + b];
#pragma unroll
    for (int o = 0; o < 6; ++o)
#pragma unroll
      for (int i = 0; i < 2; ++i)
#pragma unroll
        for (int j = 0; j < 2; ++j) {
          // weights: block-uniform addresses -> scalar loads
          const float* wp =
              &w1[((size_t)((o * 3 + c) * 28 + (2 * ph + i)) * 28 + (2 * pw + j)) * 25];
#pragma unroll
          for (int dh = 0; dh < 5; ++dh)
#pragma unroll
            for (int dw = 0; dw < 5; ++dw)
              acc[o][i][j] = fmaf(xw[i + dh][j + dw], wp[dh * 5 + dw], acc[o][i][j]);
        }
  }

#pragma unroll
  for (int o = 0; o < 6; ++o) {
    float v[2][2];
#pragma unroll
    for (int i = 0; i < 2; ++i)
#pragma unroll
      for (int j = 0; j < 2; ++j) {
        const float bias = b1[(size_t)(o * 28 + (2 * ph + i)) * 28 + (2 * pw + j)];
        v[i][j] = fmaxf(acc[o][i][j] + bias, 0.f);
      }
    const float m = fmaxf(fmaxf(v[0][0], v[0][1]), fmaxf(v[1][0], v[1][1]));
    h1[((size_t)(o * 14 + ph) * 14 + pw) * NB + b] = m;
  }
}

// ---------------------------------------------------------------------------
// K2: untied conv2 (C=6,k=5, 14x14 -> 10x10, O=16) + bias + relu + 2x2 maxpool
//     h1: (6,14,14,B)  w2: (16,6,10,10,25)  b2: (16,10,10)  h2: (16,5,5,B)
//     blockIdx.x = pooled pos (5x5); .y = o-group (4 o's); .z = bgroup
// ---------------------------------------------------------------------------
__global__ __launch_bounds__(256) void k_conv2(const float* __restrict__ h1,
                                               const float* __restrict__ w2,
                                               const float* __restrict__ b2,
                                               float* __restrict__ h2) {
  const int pos = blockIdx.x;            // 0..24
  const int ph = pos / 5, pw = pos % 5;
  const int og = blockIdx.y;             // 0..3
  const int b = blockIdx.z * 256 + threadIdx.x;

  float acc[4][2][2];
#pragma unroll
  for (int oo = 0; oo < 4; ++oo)
#pragma unroll
    for (int i = 0; i < 2; ++i)
#pragma unroll
      for (int j = 0; j < 2; ++j) acc[oo][i][j] = 0.f;

  for (int c = 0; c < 6; ++c) {
    float xw[6][6];
#pragma unroll
    for (int dh = 0; dh < 6; ++dh)
#pragma unroll
      for (int dw = 0; dw < 6; ++dw)
        xw[dh][dw] =
            h1[((size_t)(c * 14 + (2 * ph + dh)) * 14 + (2 * pw + dw)) * NB + b];
#pragma unroll
    for (int oo = 0; oo < 4; ++oo) {
      const int o = og * 4 + oo;
#pragma unroll
      for (int i = 0; i < 2; ++i)
#pragma unroll
        for (int j = 0; j < 2; ++j) {
          const float* wp =
              &w2[((size_t)((o * 6 + c) * 10 + (2 * ph + i)) * 10 + (2 * pw + j)) * 25];
#pragma unroll
          for (int p = 0; p < 25; ++p)
            acc[oo][i][j] = fmaf(xw[i + p / 5][j + p % 5], wp[p], acc[oo][i][j]);
        }
    }
  }

#pragma unroll
  for (int oo = 0; oo < 4; ++oo) {
    const int o = og * 4 + oo;
    float v[2][2];
#pragma unroll
    for (int i = 0; i < 2; ++i)
#pragma unroll
      for (int j = 0; j < 2; ++j) {
        const float bias = b2[(size_t)(o * 10 + (2 * ph + i)) * 10 + (2 * pw + j)];
        v[i][j] = fmaxf(acc[oo][i][j] + bias, 0.f);
      }
    const float m = fmaxf(fmaxf(v[0][0], v[0][1]), fmaxf(v[1][0], v[1][1]));
    h2[((size_t)(o * 5 + ph) * 5 + pw) * NB + b] = m;
  }
}

// ---------------------------------------------------------------------------
// K3: conv3 == GEMM: h3[o,b] = relu( sum_k w3[o,k] * h2[k,b] + b3[o] ), k=400
//     h2 layout (16,5,5,B) flattens to (k=c*25+dh*5+dw, b) which matches w3's
//     (o, c, p) flattening exactly.
//     blockIdx.x = o-group (4 o's, 30 groups); .y = bgroup
// ---------------------------------------------------------------------------
__global__ __launch_bounds__(256) void k_conv3(const float* __restrict__ h2,
                                               const float* __restrict__ w3,
                                               const float* __restrict__ b3,
                                               float* __restrict__ h3) {
  const int og = blockIdx.x;             // 0..29
  const int b = blockIdx.y * 256 + threadIdx.x;
  float acc[4] = {0.f, 0.f, 0.f, 0.f};
#pragma unroll 8
  for (int k = 0; k < 400; ++k) {
    const float xv = h2[(size_t)k * NB + b];
#pragma unroll
    for (int i = 0; i < 4; ++i)
      acc[i] = fmaf(xv, w3[(size_t)(og * 4 + i) * 400 + k], acc[i]);
  }
#pragma unroll
  for (int i = 0; i < 4; ++i)
    h3[(size_t)(og * 4 + i) * NB + b] = fmaxf(acc[i] + b3[og * 4 + i], 0.f);
}

// ---------------------------------------------------------------------------
// K4: FC tail fused: h4 = relu(h3 @ fc2_w.T + fc2_b); out = h4 @ fc3_w.T + fc3_b
//     h3: (120,B)  fc2_w: (84,120)  fc3_w: (10,84)  out: (B,10)
//     block = 64-batch tile, h3/h4 tiles staged in LDS
// ---------------------------------------------------------------------------
__global__ __launch_bounds__(256) void k_fc(const float* __restrict__ h3,
                                            const float* __restrict__ fc2w,
                                            const float* __restrict__ fc2b,
                                            const float* __restrict__ fc3w,
                                            const float* __restrict__ fc3b,
                                            float* __restrict__ out) {
  __shared__ float h3L[120 * 64];
  __shared__ float h4L[84 * 64];
  const int b0 = blockIdx.x * 64;

  for (int idx = threadIdx.x; idx < 120 * 64; idx += 256) {
    const int k = idx >> 6, bb = idx & 63;
    h3L[idx] = h3[(size_t)k * NB + b0 + bb];
  }
  __syncthreads();

#pragma unroll
  for (int s = 0; s < 21; ++s) {          // 84*64 / 256
    const int t = s * 256 + threadIdx.x;
    const int j = t >> 6, bb = t & 63;    // j wave-uniform
    float acc = fc2b[j];
#pragma unroll 8
    for (int k = 0; k < 120; ++k)
      acc = fmaf(h3L[k * 64 + bb], fc2w[j * 120 + k], acc);
    h4L[j * 64 + bb] = fmaxf(acc, 0.f);
  }
  __syncthreads();

  for (int s = 0; s < 3; ++s) {           // 10*64 = 640 outputs
    const int t = s * 256 + threadIdx.x;
    if (t < 640) {
      const int i = t >> 6, bb = t & 63;  // i wave-uniform
      float acc = fc3b[i];
#pragma unroll 4
      for (int j = 0; j < 84; ++j)
        acc = fmaf(h4L[j * 64 + bb], fc3w[i * 84 + j], acc);
      out[(size_t)(b0 + bb) * 10 + i] = acc;
    }
  }
}

// ---------------------------------------------------------------------------
extern "C" void kernel_launch(void* const* d_in, const int* in_sizes, int n_in,
                              void* d_out, int out_size, void* d_ws, size_t ws_size,
                              hipStream_t stream) {
  const float* x    = (const float*)d_in[0];
  const float* w1   = (const float*)d_in[1];
  const float* b1   = (const float*)d_in[2];
  const float* w2   = (const float*)d_in[3];
  const float* b2   = (const float*)d_in[4];
  const float* w3   = (const float*)d_in[5];
  const float* b3   = (const float*)d_in[6];
  const float* fc2w = (const float*)d_in[7];
  const float* fc2b = (const float*)d_in[8];
  const float* fc3w = (const float*)d_in[9];
  const float* fc3b = (const float*)d_in[10];
  float* out = (float*)d_out;

  float* ws = (float*)d_ws;
  float* xT = ws;                         // 3*32*32*1024  = 3,145,728 f
  float* h1 = xT + 3145728;               // 6*14*14*1024  = 1,204,224 f
  float* h2 = h1 + 1204224;               // 16*5*5*1024   =   409,600 f
  float* h3 = h2 + 409600;                // 120*1024      =   122,880 f
                                          // total ~19.5 MB of d_ws

  k_transpose<<<dim3(48, 16), 256, 0, stream>>>(x, xT);
  k_conv1<<<dim3(196, 4), 256, 0, stream>>>(xT, w1, b1, h1);
  k_conv2<<<dim3(25, 4, 4), 256, 0, stream>>>(h1, w2, b2, h2);
  k_conv3<<<dim3(30, 4), 256, 0, stream>>>(h2, w3, b3, h3);
  k_fc<<<dim3(16), 256, 0, stream>>>(h3, fc2w, fc2b, fc3w, fc3b, out);
}

// Round 2
// 168.703 us; speedup vs baseline: 1.3594x; 1.3594x over previous
//
#include <hip/hip_runtime.h>
#include <math.h>

#define NB 1024  // batch

// ---------------------------------------------------------------------------
// K0: transpose x (B, C*H*W=3072) -> xT (3072, B), 64x64 LDS tiles
// ---------------------------------------------------------------------------
__global__ __launch_bounds__(256) void k_transpose(const float* __restrict__ x,
                                                   float* __restrict__ xT) {
  __shared__ float tile[64][65];
  const int c0 = blockIdx.x * 64;   // chw tile
  const int b0 = blockIdx.y * 64;   // batch tile
  const int tx = threadIdx.x & 63;
  const int ty = threadIdx.x >> 6;
#pragma unroll
  for (int r = 0; r < 16; ++r) {
    const int bb = r * 4 + ty;
    tile[bb][tx] = x[(size_t)(b0 + bb) * 3072 + c0 + tx];  // coalesced over chw
  }
  __syncthreads();
#pragma unroll
  for (int r = 0; r < 16; ++r) {
    const int cc = r * 4 + ty;
    xT[(size_t)(c0 + cc) * NB + b0 + tx] = tile[tx][cc];   // coalesced over b
  }
}

// ---------------------------------------------------------------------------
// K1: untied conv1 (C=3,k=5, 32x32 -> 28x28, O=6) + bias + relu + 2x2 maxpool
//     xT: (3,32,32,B)  w1: (6,3,28,28,25)  b1: (6,28,28)  h1: (6,14,14,B)
// ---------------------------------------------------------------------------
__global__ __launch_bounds__(256) void k_conv1(const float* __restrict__ xT,
                                               const float* __restrict__ w1,
                                               const float* __restrict__ b1,
                                               float* __restrict__ h1) {
  const int pos = blockIdx.x;            // 0..195
  const int ph = pos / 14, pw = pos % 14;
  const int b = blockIdx.y * 256 + threadIdx.x;

  float acc[6][2][2];
#pragma unroll
  for (int o = 0; o < 6; ++o)
#pragma unroll
    for (int i = 0; i < 2; ++i)
#pragma unroll
      for (int j = 0; j < 2; ++j) acc[o][i][j] = 0.f;

  for (int c = 0; c < 3; ++c) {
    float xw[6][6];
#pragma unroll
    for (int dh = 0; dh < 6; ++dh)
#pragma unroll
      for (int dw = 0; dw < 6; ++dw)
        xw[dh][dw] =
            xT[((size_t)(c * 32 + (2 * ph + dh)) * 32 + (2 * pw + dw)) * NB + b];
#pragma unroll
    for (int o = 0; o < 6; ++o)
#pragma unroll
      for (int i = 0; i < 2; ++i)
#pragma unroll
        for (int j = 0; j < 2; ++j) {
          const float* wp =
              &w1[((size_t)((o * 3 + c) * 28 + (2 * ph + i)) * 28 + (2 * pw + j)) * 25];
#pragma unroll
          for (int dh = 0; dh < 5; ++dh)
#pragma unroll
            for (int dw = 0; dw < 5; ++dw)
              acc[o][i][j] = fmaf(xw[i + dh][j + dw], wp[dh * 5 + dw], acc[o][i][j]);
        }
  }

#pragma unroll
  for (int o = 0; o < 6; ++o) {
    float v[2][2];
#pragma unroll
    for (int i = 0; i < 2; ++i)
#pragma unroll
      for (int j = 0; j < 2; ++j) {
        const float bias = b1[(size_t)(o * 28 + (2 * ph + i)) * 28 + (2 * pw + j)];
        v[i][j] = fmaxf(acc[o][i][j] + bias, 0.f);
      }
    const float m = fmaxf(fmaxf(v[0][0], v[0][1]), fmaxf(v[1][0], v[1][1]));
    h1[((size_t)(o * 14 + ph) * 14 + pw) * NB + b] = m;
  }
}

// ---------------------------------------------------------------------------
// K2: untied conv2 (C=6,k=5, 14x14 -> 10x10, O=16) + bias + relu + 2x2 maxpool
//     h1: (6,14,14,B)  w2: (16,6,10,10,25)  b2: (16,10,10)  h2: (16,5,5,B)
// ---------------------------------------------------------------------------
__global__ __launch_bounds__(256) void k_conv2(const float* __restrict__ h1,
                                               const float* __restrict__ w2,
                                               const float* __restrict__ b2,
                                               float* __restrict__ h2) {
  const int pos = blockIdx.x;            // 0..24
  const int ph = pos / 5, pw = pos % 5;
  const int og = blockIdx.y;             // 0..3
  const int b = blockIdx.z * 256 + threadIdx.x;

  float acc[4][2][2];
#pragma unroll
  for (int oo = 0; oo < 4; ++oo)
#pragma unroll
    for (int i = 0; i < 2; ++i)
#pragma unroll
      for (int j = 0; j < 2; ++j) acc[oo][i][j] = 0.f;

  for (int c = 0; c < 6; ++c) {
    float xw[6][6];
#pragma unroll
    for (int dh = 0; dh < 6; ++dh)
#pragma unroll
      for (int dw = 0; dw < 6; ++dw)
        xw[dh][dw] =
            h1[((size_t)(c * 14 + (2 * ph + dh)) * 14 + (2 * pw + dw)) * NB + b];
#pragma unroll
    for (int oo = 0; oo < 4; ++oo) {
      const int o = og * 4 + oo;
#pragma unroll
      for (int i = 0; i < 2; ++i)
#pragma unroll
        for (int j = 0; j < 2; ++j) {
          const float* wp =
              &w2[((size_t)((o * 6 + c) * 10 + (2 * ph + i)) * 10 + (2 * pw + j)) * 25];
#pragma unroll
          for (int p = 0; p < 25; ++p)
            acc[oo][i][j] = fmaf(xw[i + p / 5][j + p % 5], wp[p], acc[oo][i][j]);
        }
    }
  }

#pragma unroll
  for (int oo = 0; oo < 4; ++oo) {
    const int o = og * 4 + oo;
    float v[2][2];
#pragma unroll
    for (int i = 0; i < 2; ++i)
#pragma unroll
      for (int j = 0; j < 2; ++j) {
        const float bias = b2[(size_t)(o * 10 + (2 * ph + i)) * 10 + (2 * pw + j)];
        v[i][j] = fmaxf(acc[oo][i][j] + bias, 0.f);
      }
    const float m = fmaxf(fmaxf(v[0][0], v[0][1]), fmaxf(v[1][0], v[1][1]));
    h2[((size_t)(o * 5 + ph) * 5 + pw) * NB + b] = m;
  }
}

// ---------------------------------------------------------------------------
// K3: conv3 == GEMM: h3[o,b] = relu( sum_k w3[o,k] * h2[k,b] + b3[o] ), k=400
//     One o per block -> 480 blocks (~7.5 waves/CU); 4 independent acc chains.
// ---------------------------------------------------------------------------
__global__ __launch_bounds__(256) void k_conv3(const float* __restrict__ h2,
                                               const float* __restrict__ w3,
                                               const float* __restrict__ b3,
                                               float* __restrict__ h3) {
  const int o = blockIdx.x;              // 0..119
  const int b = blockIdx.y * 256 + threadIdx.x;
  const float* __restrict__ wp = w3 + (size_t)o * 400;
  float a0 = 0.f, a1 = 0.f, a2 = 0.f, a3 = 0.f;
#pragma unroll 8
  for (int k = 0; k < 400; k += 4) {
    a0 = fmaf(h2[(size_t)(k + 0) * NB + b], wp[k + 0], a0);
    a1 = fmaf(h2[(size_t)(k + 1) * NB + b], wp[k + 1], a1);
    a2 = fmaf(h2[(size_t)(k + 2) * NB + b], wp[k + 2], a2);
    a3 = fmaf(h2[(size_t)(k + 3) * NB + b], wp[k + 3], a3);
  }
  h3[(size_t)o * NB + b] = fmaxf((a0 + a1) + (a2 + a3) + b3[o], 0.f);
}

// ---------------------------------------------------------------------------
// K4a: h4[j,b] = relu( dot(h3[:,b], fc2w[j,:]) + fc2b[j] ), j<84
//      grid (16 bgroups, 21 jgroups), block 256 = 64 b x 4 j
// ---------------------------------------------------------------------------
__global__ __launch_bounds__(256) void k_fc2(const float* __restrict__ h3,
                                             const float* __restrict__ fc2w,
                                             const float* __restrict__ fc2b,
                                             float* __restrict__ h4) {
  const int b = blockIdx.x * 64 + (threadIdx.x & 63);
  const int j = blockIdx.y * 4 + (threadIdx.x >> 6);  // wave-uniform
  const float* __restrict__ wp = fc2w + (size_t)j * 120;
  float a0 = 0.f, a1 = 0.f;
#pragma unroll
  for (int k = 0; k < 120; k += 2) {
    a0 = fmaf(h3[(size_t)(k + 0) * NB + b], wp[k + 0], a0);
    a1 = fmaf(h3[(size_t)(k + 1) * NB + b], wp[k + 1], a1);
  }
  h4[(size_t)j * NB + b] = fmaxf(a0 + a1 + fc2b[j], 0.f);
}

// ---------------------------------------------------------------------------
// K4b: out[b,i] = dot(h4[:,b], fc3w[i,:]) + fc3b[i], i<10
//      grid (16 bgroups, 3 igroups), block 256 = 64 b x 4 i (i>=10 idle)
// ---------------------------------------------------------------------------
__global__ __launch_bounds__(256) void k_fc3(const float* __restrict__ h4,
                                             const float* __restrict__ fc3w,
                                             const float* __restrict__ fc3b,
                                             float* __restrict__ out) {
  const int b = blockIdx.x * 64 + (threadIdx.x & 63);
  const int i = blockIdx.y * 4 + (threadIdx.x >> 6);  // wave-uniform
  if (i < 10) {
    const float* __restrict__ wp = fc3w + (size_t)i * 84;
    float a0 = 0.f, a1 = 0.f;
#pragma unroll
    for (int j = 0; j < 84; j += 2) {
      a0 = fmaf(h4[(size_t)(j + 0) * NB + b], wp[j + 0], a0);
      a1 = fmaf(h4[(size_t)(j + 1) * NB + b], wp[j + 1], a1);
    }
    out[(size_t)b * 10 + i] = a0 + a1 + fc3b[i];
  }
}

// ---------------------------------------------------------------------------
extern "C" void kernel_launch(void* const* d_in, const int* in_sizes, int n_in,
                              void* d_out, int out_size, void* d_ws, size_t ws_size,
                              hipStream_t stream) {
  const float* x    = (const float*)d_in[0];
  const float* w1   = (const float*)d_in[1];
  const float* b1   = (const float*)d_in[2];
  const float* w2   = (const float*)d_in[3];
  const float* b2   = (const float*)d_in[4];
  const float* w3   = (const float*)d_in[5];
  const float* b3   = (const float*)d_in[6];
  const float* fc2w = (const float*)d_in[7];
  const float* fc2b = (const float*)d_in[8];
  const float* fc3w = (const float*)d_in[9];
  const float* fc3b = (const float*)d_in[10];
  float* out = (float*)d_out;

  float* ws = (float*)d_ws;
  float* xT = ws;                         // 3*32*32*1024  = 3,145,728 f
  float* h1 = xT + 3145728;               // 6*14*14*1024  = 1,204,224 f
  float* h2 = h1 + 1204224;               // 16*5*5*1024   =   409,600 f
  float* h3 = h2 + 409600;                // 120*1024      =   122,880 f
  float* h4 = xT;                         // 84*1024 — aliases dead xT region

  k_transpose<<<dim3(48, 16), 256, 0, stream>>>(x, xT);
  k_conv1<<<dim3(196, 4), 256, 0, stream>>>(xT, w1, b1, h1);
  k_conv2<<<dim3(25, 4, 4), 256, 0, stream>>>(h1, w2, b2, h2);
  k_conv3<<<dim3(120, 4), 256, 0, stream>>>(h2, w3, b3, h3);
  k_fc2<<<dim3(16, 21), 256, 0, stream>>>(h3, fc2w, fc2b, h4);
  k_fc3<<<dim3(16, 3), 256, 0, stream>>>(h4, fc3w, fc3b, out);
}